// Round 18
// baseline (351.075 us; speedup 1.0000x reference)
//
#include <hip/hip_runtime.h>
#include <cstdint>

using u16 = unsigned short;
using u32 = unsigned int;

typedef __bf16 bf16x8 __attribute__((ext_vector_type(8)));
typedef float f32x4 __attribute__((ext_vector_type(4)));
typedef short short4v __attribute__((ext_vector_type(4)));

constexpr int TOK = 100352;                 // B * H * W
constexpr float LOG2E = 1.4426950408889634f;
constexpr float SCALE_QL = 0.25503490f;     // 1/sqrt(32) * log2e (exp2-form softmax)

__device__ __forceinline__ float bf2f(u16 u) {
  union { u32 i; float f; } z; z.i = ((u32)u) << 16; return z.f;
}
__device__ __forceinline__ u16 f2bf(float f) {
  union { float f; u32 i; } z; z.f = f;
  u32 r = z.i + 0x7FFFu + ((z.i >> 16) & 1u);
  return (u16)(r >> 16);
}
__device__ __forceinline__ u32 pk2bf(float a, float b) {
  union { __bf16 h[2]; u32 w; } z;
  z.h[0] = (__bf16)a; z.h[1] = (__bf16)b; return z.w;
}

__device__ __forceinline__ float gelu_f(float v) {
  // exp2-form tanh-gelu: v * sigmoid(2u) with 2*log2e folded into the poly.
  float t = -v * (2.3022587f + 0.10294455f * v * v);
  float e = exp2f(t);                         // native v_exp_f32
  return v * __builtin_amdgcn_rcpf(1.f + e);
}

__device__ __forceinline__ void gload_lds16(const void* g, void* l) {
  __builtin_amdgcn_global_load_lds((const __attribute__((address_space(1))) void*)g,
                                   (__attribute__((address_space(3))) void*)l, 16, 0, 0);
}

// -------------------- merged weight prep (1 launch) ------------------------------
__global__ __launch_bounds__(256) void prep_weights(
    const float* __restrict__ qkv_w, const float* __restrict__ proj_w,
    const float* __restrict__ fc1_w, const float* __restrict__ fc2_w,
    u16* __restrict__ qkvT, u16* __restrict__ projT,
    u16* __restrict__ fc1T, u16* __restrict__ fc2T)
{
  int id = blockIdx.x * 256 + threadIdx.x;
  if (id < 122880) {                       // qkvT: (640 x 192), src 192x576
    int n = id / 192, k = id - n * 192;
    float v = (n < 576) ? qkv_w[(size_t)k * 576 + n] : 0.f;
    qkvT[id] = f2bf(v);
  } else if (id < 172032) {                // projT: (256 x 192), src 192x192
    int t = id - 122880;
    int n = t / 192, k = t - n * 192;
    float v = (n < 192) ? proj_w[(size_t)k * 192 + n] : 0.f;
    projT[t] = f2bf(v);
  } else if (id < 319488) {                // fc1T swz1: [768][192], xor (row&7)
    int t = id - 172032;
    int n = t / 192, k = t - n * 192;
    int sg = (k >> 3) ^ (n & 7);
    fc1T[n * 192 + sg * 8 + (k & 7)] = f2bf(fc1_w[(size_t)k * 768 + n]);
  } else if (id < 466944) {                // fc2T swz2: [24 ch][768 granules]
    int t = id - 319488;
    int oc = t / 768, gc = t - oc * 768;
    int ch = gc >> 5, gcl = gc & 31;
    int f = gcl >> 4, gq = (gcl >> 2) & 3, e = gcl & 3;
    int P = oc * 4 + (gq ^ ((oc >> 2) & 3));
    fc2T[ch * 6144 + P * 8 + f * 4 + e] = f2bf(fc2_w[(size_t)gc * 192 + oc]);
  }
}

// -------------------- layernorm (one wave per 192-wide row) --------------------
__global__ __launch_bounds__(256) void ln_kernel(const float* __restrict__ x,
                                                 const float* __restrict__ g,
                                                 const float* __restrict__ b,
                                                 u16* __restrict__ out) {
  int row  = blockIdx.x * 4 + (threadIdx.x >> 6);
  int lane = threadIdx.x & 63;
  const float* xr = x + (size_t)row * 192;
  float v[3];
  #pragma unroll
  for (int t = 0; t < 3; ++t) v[t] = xr[lane + 64 * t];
  float s = v[0] + v[1] + v[2];
  #pragma unroll
  for (int o = 32; o; o >>= 1) s += __shfl_xor(s, o);
  float mu = s * (1.f / 192.f);
  float q = 0.f;
  #pragma unroll
  for (int t = 0; t < 3; ++t) { float d = v[t] - mu; q += d * d; }
  #pragma unroll
  for (int o = 32; o; o >>= 1) q += __shfl_xor(q, o);
  float rs = rsqrtf(q * (1.f / 192.f) + 1e-5f);
  #pragma unroll
  for (int t = 0; t < 3; ++t) {
    int c = lane + 64 * t;
    out[(size_t)row * 192 + c] = f2bf((v[t] - mu) * rs * g[c] + b[c]);
  }
}

// -------------------- QKV GEMM v2: barrier-free k-loop ---------------------------
// 128M x 64N tiles (9 N-tiles, N=576 exact). Wave owns 32 rows and stages its
// OWN [32x32] A-chunk per step into wave-private LDS (no cross-wave sharing ->
// NO s_barrier in the k-loop; per-wave counted vmcnt, reuse distance 3, all
// hazards are single-wave program order). B [64x192] (24KB) staged once before
// one __syncthreads, read-only after. Chunk-major LDS layouts (slot = c*rows+r)
// make A/B fragment b128 reads bank-conflict-free (lane stride 16B).
__global__ __launch_bounds__(256) void qkv_kernel(
    const u16* __restrict__ A, const u16* __restrict__ BT,
    const float* __restrict__ bias,
    u16* __restrict__ outb)
{
  constexpr int NWG = 7056;                 // 784 M * 9 N ; 7056/8 = 882
  __shared__ __align__(16) u16 LDS[24576];  // A: 4w x 3buf x 1024 u16 | B: 12288
  u16* Bl = LDS + 12288;

  int tid = threadIdx.x;
  int wg = blockIdx.x;
  int lin = (wg & 7) * (NWG / 8) + (wg >> 3);     // chunked XCD remap (bijective)
  int tileM = (lin / 9) * 128, tileN = (lin % 9) * 64;
  int lane = tid & 63, wave = tid >> 6;
  int g = lane >> 4, l15 = lane & 15;
  f32x4 acc[2][4] = {};

  // ---- B stage once: 1536 granules, chunk-major slot = c*64 + n ----
  #pragma unroll
  for (int rnd = 0; rnd < 6; ++rnd) {
    int s = rnd * 256 + tid;
    int c = s >> 6, n = s & 63;
    gload_lds16(BT + (size_t)(tileN + n) * 192 + c * 8, &Bl[(rnd * 256 + wave * 64) * 8]);
  }
  // ---- A stage: wave-private, chunk-major slot = c*32 + r (2 gloads/step) ----
  const u16* Arow = A + (size_t)(tileM + wave * 32) * 192;
#define ASTAGE(t) do {                                                        \
    const int b_ = (t) % 3;                                                   \
    _Pragma("unroll")                                                         \
    for (int i_ = 0; i_ < 2; ++i_) {                                          \
      int s_ = i_ * 64 + lane;                                                \
      gload_lds16(Arow + (size_t)(s_ & 31) * 192 + (t) * 32 + (s_ >> 5) * 8,  \
                  &LDS[((wave * 3 + b_) * 128 + i_ * 64) * 8]);               \
    }                                                                         \
  } while (0)

  ASTAGE(0);
  ASTAGE(1);
  __syncthreads();               // drains all: B + A bufs 0,1 ready

  int cb = tileN + g * 4;        // epilogue col base (r=0), cols always valid
  f32x4 bv4[4];
  #pragma unroll
  for (int ni = 0; ni < 4; ++ni) bv4[ni] = *(const f32x4*)&bias[cb + ni * 16];

  #pragma unroll
  for (int t = 0; t < 6; ++t) {
    if (t + 2 < 6) ASTAGE(t + 2);
    // outstanding now: A(t)2 + A(t+1)2 [+ A(t+2)2] -> wait exactly A(t)
    if (t < 4)      asm volatile("s_waitcnt vmcnt(4)" ::: "memory");
    else if (t == 4) asm volatile("s_waitcnt vmcnt(2)" ::: "memory");
    else            asm volatile("s_waitcnt vmcnt(0)" ::: "memory");
    __builtin_amdgcn_sched_barrier(0);
    const int buf = t % 3;
    bf16x8 af[2], bfr[4];
    #pragma unroll
    for (int mi = 0; mi < 2; ++mi)
      af[mi] = *(const bf16x8*)&LDS[((wave * 3 + buf) * 128 + g * 32 + mi * 16 + l15) * 8];
    #pragma unroll
    for (int ni = 0; ni < 4; ++ni)
      bfr[ni] = *(const bf16x8*)&Bl[((t * 4 + g) * 64 + ni * 16 + l15) * 8];
    #pragma unroll
    for (int mi = 0; mi < 2; ++mi)
      #pragma unroll
      for (int ni = 0; ni < 4; ++ni)   // SWAPPED operands: C^T fragment layout
        acc[mi][ni] = __builtin_amdgcn_mfma_f32_16x16x32_bf16(bfr[ni], af[mi], acc[mi][ni], 0, 0, 0);
  }
#undef ASTAGE

  // ---- epilogue: lane owns 2 rows-halves x 16 cols (4x4 consecutive) ----
  #pragma unroll
  for (int mi = 0; mi < 2; ++mi) {
    size_t row = (size_t)(tileM + wave * 32 + mi * 16 + l15);
    u16* orow = outb + row * 576 + cb;
    #pragma unroll
    for (int ni = 0; ni < 4; ++ni) {
      float v0 = acc[mi][ni][0] + bv4[ni][0];
      float v1 = acc[mi][ni][1] + bv4[ni][1];
      float v2 = acc[mi][ni][2] + bv4[ni][2];
      float v3 = acc[mi][ni][3] + bv4[ni][3];
      if ((cb + ni * 16) < 192) {          // q columns: fold scale*log2e
        v0 *= SCALE_QL; v1 *= SCALE_QL; v2 *= SCALE_QL; v3 *= SCALE_QL;
      }
      uint2 w;
      w.x = pk2bf(v0, v1);
      w.y = pk2bf(v2, v3);
      *(uint2*)&orow[ni * 16] = w;
    }
  }
}

// -------------------- fused proj + residual + LN2 --------------------------------
__global__ __launch_bounds__(256, 2) void proj_ln(
    const u16* __restrict__ A,      // attnO [TOK][192] bf16
    const u16* __restrict__ BT,     // projT [256][192] bf16 (rows 0..191 used)
    const float* __restrict__ bias,
    const float* __restrict__ x,
    const float* __restrict__ n2g, const float* __restrict__ n2b,
    float* __restrict__ resid, u16* __restrict__ h2)
{
  constexpr int NWG = 784;
  __shared__ __align__(16) u16 As[3][4096];   // 128 rows x 32 k
  __shared__ __align__(16) u16 Bs[3][6144];   // 192 rows x 32 k
  int tid = threadIdx.x;
  int wg = blockIdx.x;
  int lin = (wg & 7) * (NWG / 8) + (wg >> 3);
  int tileM = lin * 128;
  int lane = tid & 63, wave = tid >> 6;
  int g = lane >> 4, l15 = lane & 15;
  f32x4 acc[2][12] = {};

  int r0 = tid >> 2, kc = (tid & 3) * 8;
  const u16* Arow0 = A + (size_t)(tileM + r0)      * 192 + kc;
  const u16* Arow1 = A + (size_t)(tileM + r0 + 64) * 192 + kc;
  const u16* Brow[3];
  #pragma unroll
  for (int i = 0; i < 3; ++i) {
    int s = (wave * 3 + i) * 64 + lane;
    Brow[i] = BT + (size_t)(s >> 2) * 192 + (s & 3) * 8;
  }
  const int wo = wave * 512;

#define PSTAGE(buf, k0) do {                                   \
    gload_lds16(Arow0 + (k0), &As[buf][wo]);                   \
    gload_lds16(Arow1 + (k0), &As[buf][2048 + wo]);            \
    _Pragma("unroll")                                          \
    for (int i = 0; i < 3; ++i)                                \
      gload_lds16(Brow[i] + (k0), &Bs[buf][(wave * 3 + i) * 512]); \
  } while (0)

  PSTAGE(0, 0);
  PSTAGE(1, 32);

  #pragma unroll
  for (int t = 0; t < 6; ++t) {
    if (t + 1 < 6) asm volatile("s_waitcnt vmcnt(5)" ::: "memory");
    else           asm volatile("s_waitcnt vmcnt(0)" ::: "memory");
    __builtin_amdgcn_s_barrier();
    __builtin_amdgcn_sched_barrier(0);
    if (t + 2 < 6) PSTAGE((t + 2) % 3, (t + 2) * 32);
    const int cur = t % 3;
    bf16x8 af[2], bfr[12];
    #pragma unroll
    for (int mi = 0; mi < 2; ++mi)
      af[mi] = *(const bf16x8*)&As[cur][(wave * 32 + mi * 16 + l15) * 32 + g * 8];
    #pragma unroll
    for (int ni = 0; ni < 12; ++ni)
      bfr[ni] = *(const bf16x8*)&Bs[cur][(ni * 16 + l15) * 32 + g * 8];
    #pragma unroll
    for (int mi = 0; mi < 2; ++mi)
      #pragma unroll
      for (int ni = 0; ni < 12; ++ni)
        acc[mi][ni] = __builtin_amdgcn_mfma_f32_16x16x32_bf16(bfr[ni], af[mi], acc[mi][ni], 0, 0, 0);
    __builtin_amdgcn_sched_barrier(0);
  }
#undef PSTAGE

  float s1[2] = {0.f, 0.f}, s2[2] = {0.f, 0.f};
  #pragma unroll
  for (int mi = 0; mi < 2; ++mi) {
    size_t row = (size_t)(tileM + wave * 32 + mi * 16 + l15);
    #pragma unroll
    for (int ni = 0; ni < 12; ++ni) {
      int cb = ni * 16 + g * 4;
      f32x4 bv = *(const f32x4*)&bias[cb];
      f32x4 xv = *(const f32x4*)&x[row * 192 + cb];
      f32x4 o;
      #pragma unroll
      for (int r = 0; r < 4; ++r) {
        o[r] = acc[mi][ni][r] + bv[r] + xv[r];
        s1[mi] += o[r];
        s2[mi] += o[r] * o[r];
      }
      acc[mi][ni] = o;
      *(f32x4*)&resid[row * 192 + cb] = o;
    }
  }
  #pragma unroll
  for (int mi = 0; mi < 2; ++mi) {
    s1[mi] += __shfl_xor(s1[mi], 16); s1[mi] += __shfl_xor(s1[mi], 32);
    s2[mi] += __shfl_xor(s2[mi], 16); s2[mi] += __shfl_xor(s2[mi], 32);
  }
  #pragma unroll
  for (int mi = 0; mi < 2; ++mi) {
    float mu = s1[mi] * (1.f / 192.f);
    float var = s2[mi] * (1.f / 192.f) - mu * mu;
    float rs = rsqrtf(var + 1e-5f);
    size_t row = (size_t)(tileM + wave * 32 + mi * 16 + l15);
    #pragma unroll
    for (int ni = 0; ni < 12; ++ni) {
      int cb = ni * 16 + g * 4;
      f32x4 gv = *(const f32x4*)&n2g[cb];
      f32x4 bv = *(const f32x4*)&n2b[cb];
      uint2 w;
      w.x = pk2bf((acc[mi][ni][0] - mu) * rs * gv[0] + bv[0],
                  (acc[mi][ni][1] - mu) * rs * gv[1] + bv[1]);
      w.y = pk2bf((acc[mi][ni][2] - mu) * rs * gv[2] + bv[2],
                  (acc[mi][ni][3] - mu) * rs * gv[3] + bv[3]);
      *(uint2*)&h2[row * 192 + cb] = w;
    }
  }
}

// -------------------- fused MLP (R14 config: measured best, 137 us) --------------
__global__ __launch_bounds__(256, 3) void mlp_fused(
    const u16* __restrict__ h2, const float* __restrict__ resid,
    const u16* __restrict__ w1g,   // swz1 layout
    const u16* __restrict__ w2g,   // swz2 layout
    const float* __restrict__ fc1b, const float* __restrict__ fc2b,
    float* __restrict__ out)
{
  __shared__ __align__(16) u16 W1c[2][6144];   // [32 gc][192 k] swz
  __shared__ __align__(16) u16 W2c[2][6144];   // 768 x 16B granules (swz2 layout)
  __shared__ float B1s[768];
  __shared__ float B2s[192];

  int tid = threadIdx.x, lane = tid & 63, wave = tid >> 6;
  int g = lane >> 4, l15 = lane & 15;
  size_t row = (size_t)blockIdx.x * 64 + wave * 16 + l15;

  for (int c = tid; c < 768; c += 256) B1s[c] = fc1b[c];
  if (tid < 192) B2s[tid] = fc2b[tid];

  bf16x8 xf[6];
  #pragma unroll
  for (int ks = 0; ks < 6; ++ks)
    xf[ks] = *(const bf16x8*)&h2[row * 192 + ks * 32 + g * 8];

#define MSTAGE(c) do {                                                    \
    _Pragma("unroll")                                                     \
    for (int it = 0; it < 3; ++it) {                                      \
      int s = it * 256 + tid;                                             \
      gload_lds16(w1g + (size_t)(c) * 6144 + s * 8,                       \
                  &W1c[(c) & 1][(it * 256 + wave * 64) * 8]);             \
      gload_lds16(w2g + (size_t)(c) * 6144 + s * 8,                       \
                  &W2c[(c) & 1][(it * 256 + wave * 64) * 8]);             \
    }                                                                     \
  } while (0)

  MSTAGE(0);
  __syncthreads();     // drains vmcnt+lgkm: chunk0 + biases ready

  f32x4 accO[12] = {};
  const int p2sw = g ^ ((l15 >> 2) & 3);   // fc2 granule swizzle (lane-const)

  #pragma unroll 2
  for (int c = 0; c < 24; ++c) {
    asm volatile("s_waitcnt vmcnt(0)" ::: "memory");   // chunk c's writes landed
    __builtin_amdgcn_s_barrier();                      // ... in ALL waves
    __builtin_amdgcn_sched_barrier(0);
    if (c + 1 < 24) MSTAGE(c + 1);                     // overwrite after barrier
    const int bs = c & 1;

    // ---- fc1 chunk: acc1[f] r = S[gelu col c*32+f*16+g*4+r][row l15] ----
    f32x4 acc1[2] = {};
    #pragma unroll
    for (int ks = 0; ks < 6; ++ks) {
      #pragma unroll
      for (int f = 0; f < 2; ++f) {
        int rl = f * 16 + l15;
        int sg = (ks * 4 + g) ^ (rl & 7);
        bf16x8 wf = *(const bf16x8*)&W1c[bs][rl * 192 + sg * 8];
        acc1[f] = __builtin_amdgcn_mfma_f32_16x16x32_bf16(wf, xf[ks], acc1[f], 0, 0, 0);
      }
    }
    // ---- bias + gelu + in-lane pack to k=16 B-frags (no LDS round-trip) ----
    short4v bp[2];
    #pragma unroll
    for (int f = 0; f < 2; ++f) {
      f32x4 bv = *(const f32x4*)&B1s[c * 32 + f * 16 + g * 4];
      float p0 = gelu_f(acc1[f][0] + bv[0]);
      float p1 = gelu_f(acc1[f][1] + bv[1]);
      float p2 = gelu_f(acc1[f][2] + bv[2]);
      float p3 = gelu_f(acc1[f][3] + bv[3]);
      union { u32 w[2]; short4v v; } uu;
      uu.w[0] = pk2bf(p0, p1);
      uu.w[1] = pk2bf(p2, p3);
      bp[f] = uu.v;
    }
    // ---- fc2 accumulate: one b128/lane per n, halves feed both k=16 MFMAs ----
    #pragma unroll
    for (int n = 0; n < 12; ++n) {
      int oc = n * 16 + l15;
      int P = oc * 4 + p2sw;
      union { bf16x8 v8; short4v h[2]; } wu;
      wu.v8 = *(const bf16x8*)&W2c[bs][P * 8];
      accO[n] = __builtin_amdgcn_mfma_f32_16x16x16bf16_1k(wu.h[0], bp[0], accO[n], 0, 0, 0);
      accO[n] = __builtin_amdgcn_mfma_f32_16x16x16bf16_1k(wu.h[1], bp[1], accO[n], 0, 0, 0);
    }
    __builtin_amdgcn_sched_barrier(0);   // pin this chunk's reads above next iter
  }
#undef MSTAGE

  // ---- epilogue: out = accO + fc2_b + resid (packed f32x4 stores) ----
  const float* rrow = resid + row * 192;
  float*      orow = out + row * 192;
  #pragma unroll
  for (int n = 0; n < 12; ++n) {
    int cb = n * 16 + g * 4;
    f32x4 bv = *(const f32x4*)&B2s[cb];
    f32x4 rv = *(const f32x4*)&rrow[cb];
    f32x4 o;
    o[0] = accO[n][0] + bv[0] + rv[0];
    o[1] = accO[n][1] + bv[1] + rv[1];
    o[2] = accO[n][2] + bv[2] + rv[2];
    o[3] = accO[n][3] + bv[3] + rv[3];
    *(f32x4*)&orow[cb] = o;
  }
}

// -------------------- MFMA windowed attention v3 (31.7 KB LDS, 1 barrier) -------
__global__ __launch_bounds__(384, 4) void attn_kernel(const u16* __restrict__ qkv,
                                                      const float* __restrict__ rpe,
                                                      u16* __restrict__ aout) {
  __shared__ __align__(16) u16 VT[192 * 72];   // V^T [d][token], pad cols zeroed
  __shared__ float RPE[1014];                  // 169 * 6, pre-scaled by log2e

  int tid = threadIdx.x;
  int win = blockIdx.x;
  int b = win >> 6, rem = win & 63, wh = rem >> 3, ww = rem & 7;
  const size_t wbase = (size_t)b * 3136 + (size_t)(wh * 7) * 56 + ww * 7;

  for (int c = tid; c < 1176; c += 384) {       // 24 d-chunks * 49 tokens (V^T)
    int dchunk = c / 49, tkn = c - dchunk * 49;
    int d0 = dchunk * 8;
    int yi = tkn / 7, xi = tkn - yi * 7;
    size_t t = wbase + yi * 56 + xi;
    uint4 v = *(const uint4*)&qkv[t * 576 + 384 + d0];
    const u16* e = (const u16*)&v;
    #pragma unroll
    for (int u = 0; u < 8; ++u) VT[(d0 + u) * 72 + tkn] = e[u];
  }
  for (int c = tid; c < 2880; c += 384) {       // zero VT pad cols 49..63
    int d = c / 15, n = 49 + (c - d * 15);
    VT[d * 72 + n] = 0;
  }
  for (int c = tid; c < 1014; c += 384) RPE[c] = rpe[c] * LOG2E;
  __syncthreads();

  int wave = tid >> 6, lane = tid & 63;
  int g = lane >> 4, l15 = lane & 15;
  int h = wave;

  bf16x8 afk[4], bfq[4];
  #pragma unroll
  for (int f = 0; f < 4; ++f) {
    int row = f * 16 + l15; row = min(row, 48);
    int y = row / 7, xx = row - y * 7;
    const u16* base = &qkv[(wbase + (size_t)y * 56 + xx) * 576];
    bfq[f] = *(const bf16x8*)(base + h * 32 + g * 8);          // Q (scaled)
    afk[f] = *(const bf16x8*)(base + 192 + h * 32 + g * 8);    // K
  }

  f32x4 acc[4][4] = {};
  __builtin_amdgcn_s_setprio(1);
  #pragma unroll
  for (int mj = 0; mj < 4; ++mj)
    #pragma unroll
    for (int ni = 0; ni < 4; ++ni)
      acc[mj][ni] = __builtin_amdgcn_mfma_f32_16x16x32_bf16(afk[mj], bfq[ni], acc[mj][ni], 0, 0, 0);
  __builtin_amdgcn_s_setprio(0);

  float sums[4];
  short4v bp[4][4];
  #pragma unroll
  for (int ni = 0; ni < 4; ++ni) {
    int i = ni * 16 + l15;
    int yi = i / 7, xi = i - yi * 7;
    #pragma unroll
    for (int mj = 0; mj < 4; ++mj)
      #pragma unroll
      for (int r = 0; r < 4; ++r) {
        int j = mj * 16 + g * 4 + r;
        int yj = j / 7, xj = j - yj * 7;
        int idx = (yi - yj + 6) * 13 + (xi - xj + 6);
        idx = max(0, min(idx, 168));
        float s = acc[mj][ni][r] + RPE[idx * 6 + h];
        acc[mj][ni][r] = (j < 49) ? s : -1e30f;
      }
    float m = -1e30f;
    #pragma unroll
    for (int mj = 0; mj < 4; ++mj) {
      f32x4 a = acc[mj][ni];
      m = fmaxf(m, fmaxf(fmaxf(a[0], a[1]), fmaxf(a[2], a[3])));
    }
    m = fmaxf(m, __shfl_xor(m, 16));
    m = fmaxf(m, __shfl_xor(m, 32));
    float sum = 0.f;
    #pragma unroll
    for (int mj = 0; mj < 4; ++mj) {
      float p0 = exp2f(acc[mj][ni][0] - m);
      float p1 = exp2f(acc[mj][ni][1] - m);
      float p2 = exp2f(acc[mj][ni][2] - m);
      float p3 = exp2f(acc[mj][ni][3] - m);
      sum += (p0 + p1) + (p2 + p3);
      union { u32 w[2]; short4v v; } uu;
      uu.w[0] = pk2bf(p0, p1);
      uu.w[1] = pk2bf(p2, p3);
      bp[ni][mj] = uu.v;
    }
    sum += __shfl_xor(sum, 16);
    sum += __shfl_xor(sum, 32);
    sums[ni] = sum;
  }

  f32x4 accO[2][4] = {};
  #pragma unroll
  for (int ks = 0; ks < 4; ++ks) {
    short4v av[2];
    #pragma unroll
    for (int md = 0; md < 2; ++md)
      av[md] = *(const short4v*)&VT[(h * 32 + md * 16 + l15) * 72 + ks * 16 + g * 4];
    __builtin_amdgcn_s_setprio(1);
    #pragma unroll
    for (int md = 0; md < 2; ++md)
      #pragma unroll
      for (int ni = 0; ni < 4; ++ni)
        accO[md][ni] = __builtin_amdgcn_mfma_f32_16x16x16bf16_1k(av[md], bp[ni][ks], accO[md][ni], 0, 0, 0);
    __builtin_amdgcn_s_setprio(0);
  }

  #pragma unroll
  for (int ni = 0; ni < 4; ++ni) {
    int i = ni * 16 + l15;
    if (i >= 49) continue;
    float inv = __builtin_amdgcn_rcpf(sums[ni]);
    int y = i / 7, xx = i - y * 7;
    u16* orow = &aout[(wbase + (size_t)y * 56 + xx) * 192 + h * 32];
    #pragma unroll
    for (int md = 0; md < 2; ++md) {
      int d0 = md * 16 + g * 4;
      *(u32*)&orow[d0]     = pk2bf(accO[md][ni][0] * inv, accO[md][ni][1] * inv);
      *(u32*)&orow[d0 + 2] = pk2bf(accO[md][ni][2] * inv, accO[md][ni][3] * inv);
    }
  }
}

// -------------------- host launch --------------------
extern "C" void kernel_launch(void* const* d_in, const int* in_sizes, int n_in,
                              void* d_out, int out_size, void* d_ws, size_t ws_size,
                              hipStream_t stream) {
  const float* x      = (const float*)d_in[0];
  const float* n1g    = (const float*)d_in[1];
  const float* n1b    = (const float*)d_in[2];
  const float* qkv_w  = (const float*)d_in[3];
  const float* qkv_b  = (const float*)d_in[4];
  const float* rpe    = (const float*)d_in[5];
  const float* proj_w = (const float*)d_in[6];
  const float* proj_b = (const float*)d_in[7];
  const float* n2g    = (const float*)d_in[8];
  const float* n2b    = (const float*)d_in[9];
  const float* fc1_w  = (const float*)d_in[10];
  const float* fc1_b  = (const float*)d_in[11];
  const float* fc2_w  = (const float*)d_in[12];
  const float* fc2_b  = (const float*)d_in[13];
  float* out = (float*)d_out;
  char* ws = (char*)d_ws;

  // workspace layout (bytes):
  u16* qkvT  = (u16*)(ws + 0);            //  640x192 bf16      [0 .. 245760)
  u16* projT = (u16*)(ws + 245760);       //  256x192           [.. 344064)
  u16* fc1T  = (u16*)(ws + 344064);       //  768x192 swz       [.. 638976)
  u16* fc2T  = (u16*)(ws + 638976);       //  24x768x8 swz      [.. 933888)
  u16* ln1   = (u16*)(ws + 1048576);      //  TOKx192 bf16; reused as attn_out
  u16* qkvB  = (u16*)(ws + 39583744);     //  TOKx576 bf16; head reused as h2
  float* resid = (float*)(ws + 78118912); //  TOKx192 f32  (ends 155189248)
  u16* attnO = ln1;
  u16* h2    = qkvB;
  if (ws_size < 193724416u) return;

  prep_weights<<<1824, 256, 0, stream>>>(qkv_w, proj_w, fc1_w, fc2_w,
                                         qkvT, projT, fc1T, fc2T);

  ln_kernel<<<TOK/4, 256, 0, stream>>>(x, n1g, n1b, ln1);

  // QKV v2: 784 M x 9 N (64-wide) = 7056 blocks, barrier-free k-loop
  qkv_kernel<<<7056, 256, 0, stream>>>(ln1, qkvT, qkv_b, qkvB);

  attn_kernel<<<2048, 384, 0, stream>>>(qkvB, rpe, attnO);

  // fused proj + residual + LN2
  proj_ln<<<784, 256, 0, stream>>>(
      attnO, projT, proj_b, x, n2g, n2b, resid, h2);

  // fused MLP: 4 waves x 16 rows, 64 rows/block, 1568 blocks (R14 config)
  mlp_fused<<<TOK/64, 256, 0, stream>>>(
      h2, resid, fc1T, fc2T, fc1_b, fc2_b, out);
}

// Round 19
// 319.098 us; speedup vs baseline: 1.1002x; 1.1002x over previous
//
#include <hip/hip_runtime.h>
#include <cstdint>

using u16 = unsigned short;
using u32 = unsigned int;

typedef __bf16 bf16x8 __attribute__((ext_vector_type(8)));
typedef float f32x4 __attribute__((ext_vector_type(4)));
typedef short short4v __attribute__((ext_vector_type(4)));

constexpr int TOK = 100352;                 // B * H * W
constexpr float LOG2E = 1.4426950408889634f;
constexpr float SCALE_QL = 0.25503490f;     // 1/sqrt(32) * log2e (exp2-form softmax)

__device__ __forceinline__ float bf2f(u16 u) {
  union { u32 i; float f; } z; z.i = ((u32)u) << 16; return z.f;
}
__device__ __forceinline__ u16 f2bf(float f) {
  union { float f; u32 i; } z; z.f = f;
  u32 r = z.i + 0x7FFFu + ((z.i >> 16) & 1u);
  return (u16)(r >> 16);
}
__device__ __forceinline__ u32 pk2bf(float a, float b) {
  union { __bf16 h[2]; u32 w; } z;
  z.h[0] = (__bf16)a; z.h[1] = (__bf16)b; return z.w;
}

__device__ __forceinline__ float gelu_f(float v) {
  // exp2-form tanh-gelu: v * sigmoid(2u) with 2*log2e folded into the poly.
  float t = -v * (2.3022587f + 0.10294455f * v * v);
  float e = exp2f(t);                         // native v_exp_f32
  return v * __builtin_amdgcn_rcpf(1.f + e);
}

__device__ __forceinline__ void gload_lds16(const void* g, void* l) {
  __builtin_amdgcn_global_load_lds((const __attribute__((address_space(1))) void*)g,
                                   (__attribute__((address_space(3))) void*)l, 16, 0, 0);
}

// -------------------- merged weight prep (1 launch) ------------------------------
__global__ __launch_bounds__(256) void prep_weights(
    const float* __restrict__ qkv_w, const float* __restrict__ proj_w,
    const float* __restrict__ fc1_w, const float* __restrict__ fc2_w,
    u16* __restrict__ qkvT, u16* __restrict__ projT,
    u16* __restrict__ fc1T, u16* __restrict__ fc2T)
{
  int id = blockIdx.x * 256 + threadIdx.x;
  if (id < 122880) {                       // qkvT: (640 x 192), src 192x576
    int n = id / 192, k = id - n * 192;
    float v = (n < 576) ? qkv_w[(size_t)k * 576 + n] : 0.f;
    qkvT[id] = f2bf(v);
  } else if (id < 172032) {                // projT: (256 x 192), src 192x192
    int t = id - 122880;
    int n = t / 192, k = t - n * 192;
    float v = (n < 192) ? proj_w[(size_t)k * 192 + n] : 0.f;
    projT[t] = f2bf(v);
  } else if (id < 319488) {                // fc1T swz1: [768][192], xor (row&7)
    int t = id - 172032;
    int n = t / 192, k = t - n * 192;
    int sg = (k >> 3) ^ (n & 7);
    fc1T[n * 192 + sg * 8 + (k & 7)] = f2bf(fc1_w[(size_t)k * 768 + n]);
  } else if (id < 466944) {                // fc2T swz2: [24 ch][768 granules]
    int t = id - 319488;
    int oc = t / 768, gc = t - oc * 768;
    int ch = gc >> 5, gcl = gc & 31;
    int f = gcl >> 4, gq = (gcl >> 2) & 3, e = gcl & 3;
    int P = oc * 4 + (gq ^ ((oc >> 2) & 3));
    fc2T[ch * 6144 + P * 8 + f * 4 + e] = f2bf(fc2_w[(size_t)gc * 192 + oc]);
  }
}

// -------------------- layernorm (one wave per 192-wide row) --------------------
__global__ __launch_bounds__(256) void ln_kernel(const float* __restrict__ x,
                                                 const float* __restrict__ g,
                                                 const float* __restrict__ b,
                                                 u16* __restrict__ out) {
  int row  = blockIdx.x * 4 + (threadIdx.x >> 6);
  int lane = threadIdx.x & 63;
  const float* xr = x + (size_t)row * 192;
  float v[3];
  #pragma unroll
  for (int t = 0; t < 3; ++t) v[t] = xr[lane + 64 * t];
  float s = v[0] + v[1] + v[2];
  #pragma unroll
  for (int o = 32; o; o >>= 1) s += __shfl_xor(s, o);
  float mu = s * (1.f / 192.f);
  float q = 0.f;
  #pragma unroll
  for (int t = 0; t < 3; ++t) { float d = v[t] - mu; q += d * d; }
  #pragma unroll
  for (int o = 32; o; o >>= 1) q += __shfl_xor(q, o);
  float rs = rsqrtf(q * (1.f / 192.f) + 1e-5f);
  #pragma unroll
  for (int t = 0; t < 3; ++t) {
    int c = lane + 64 * t;
    out[(size_t)row * 192 + c] = f2bf((v[t] - mu) * rs * g[c] + b[c]);
  }
}

// -------------------- MFMA GEMM: 3-buffer pipeline, counted vmcnt (R14/R17) ------
enum { MQKV = 0 };

template<int MODE, int MT, int NT, int N, int K, int LDC>
__global__ __launch_bounds__(256) void gemm_kernel(
    const u16* __restrict__ A, const u16* __restrict__ BT,
    const float* __restrict__ bias,
    u16* __restrict__ outb)
{
  constexpr int NWG = MT * NT;          // all call sites: NWG % 8 == 0
  constexpr int NTL = K / 32;
  __shared__ __align__(16) u16 As[3][4096];
  __shared__ __align__(16) u16 Bs[3][4096];
  int tid = threadIdx.x;
  int wg = blockIdx.x;
  int lin = (wg & 7) * (NWG / 8) + (wg >> 3);   // chunked XCD remap (bijective)
  int tileM = (lin / NT) * 128, tileN = (lin % NT) * 128;
  int lane = tid & 63, wave = tid >> 6;
  int wm = wave >> 1, wn = wave & 1;
  int g = lane >> 4, l15 = lane & 15;
  f32x4 acc[4][4] = {};

  int r0 = tid >> 2, kc = (tid & 3) * 8;
  const u16* Arow0 = A  + (size_t)(tileM + r0)      * K + kc;
  const u16* Arow1 = A  + (size_t)(tileM + r0 + 64) * K + kc;
  const u16* Brow0 = BT + (size_t)(tileN + r0)      * K + kc;
  const u16* Brow1 = BT + (size_t)(tileN + r0 + 64) * K + kc;
  const int wo = wave * 512;

#define GSTAGE(buf, k0) do {                              \
    gload_lds16(Arow0 + (k0), &As[buf][wo]);              \
    gload_lds16(Arow1 + (k0), &As[buf][2048 + wo]);       \
    gload_lds16(Brow0 + (k0), &Bs[buf][wo]);              \
    gload_lds16(Brow1 + (k0), &Bs[buf][2048 + wo]);       \
  } while (0)

  GSTAGE(0, 0);
  GSTAGE(1, 32);

  #pragma unroll
  for (int t = 0; t < NTL; ++t) {
    if (t + 1 < NTL) asm volatile("s_waitcnt vmcnt(4)" ::: "memory");
    else             asm volatile("s_waitcnt vmcnt(0)" ::: "memory");
    __builtin_amdgcn_s_barrier();
    __builtin_amdgcn_sched_barrier(0);
    if (t + 2 < NTL) GSTAGE((t + 2) % 3, (t + 2) * 32);
    const int cur = t % 3;
    bf16x8 af[4], bfr[4];
    #pragma unroll
    for (int mi = 0; mi < 4; ++mi)
      af[mi] = *(const bf16x8*)&As[cur][(wm * 64 + mi * 16 + l15) * 32 + g * 8];
    #pragma unroll
    for (int ni = 0; ni < 4; ++ni)
      bfr[ni] = *(const bf16x8*)&Bs[cur][(wn * 64 + ni * 16 + l15) * 32 + g * 8];
    #pragma unroll
    for (int mi = 0; mi < 4; ++mi)
      #pragma unroll
      for (int ni = 0; ni < 4; ++ni)   // SWAPPED operands: C^T fragment layout
        acc[mi][ni] = __builtin_amdgcn_mfma_f32_16x16x32_bf16(bfr[ni], af[mi], acc[mi][ni], 0, 0, 0);
    __builtin_amdgcn_sched_barrier(0);   // pin reads above next iter's overwrite
  }
#undef GSTAGE

  int cb = tileN + wn * 64 + g * 4;
  f32x4 bv4[4];
  bool cok[4];
  #pragma unroll
  for (int ni = 0; ni < 4; ++ni) {
    cok[ni] = (cb + ni * 16) < N;
    bv4[ni] = cok[ni] ? *(const f32x4*)&bias[cb + ni * 16] : f32x4{};
  }
  #pragma unroll
  for (int mi = 0; mi < 4; ++mi) {
    size_t row = (size_t)(tileM + wm * 64 + mi * 16 + l15);
    u16* orow = outb + row * LDC + cb;
    #pragma unroll
    for (int ni = 0; ni < 4; ++ni) {
      if (!cok[ni]) continue;
      float v0 = acc[mi][ni][0] + bv4[ni][0];
      float v1 = acc[mi][ni][1] + bv4[ni][1];
      float v2 = acc[mi][ni][2] + bv4[ni][2];
      float v3 = acc[mi][ni][3] + bv4[ni][3];
      if (MODE == MQKV && (cb + ni * 16) < 192) {
        v0 *= SCALE_QL; v1 *= SCALE_QL; v2 *= SCALE_QL; v3 *= SCALE_QL;
      }
      uint2 w;
      w.x = pk2bf(v0, v1);
      w.y = pk2bf(v2, v3);
      *(uint2*)&orow[ni * 16] = w;
    }
  }
}

// -------------------- fused proj + residual + LN2 (resid now bf16) ---------------
__global__ __launch_bounds__(256, 2) void proj_ln(
    const u16* __restrict__ A,      // attnO [TOK][192] bf16
    const u16* __restrict__ BT,     // projT [256][192] bf16 (rows 0..191 used)
    const float* __restrict__ bias,
    const float* __restrict__ x,
    const float* __restrict__ n2g, const float* __restrict__ n2b,
    u16* __restrict__ resid, u16* __restrict__ h2)
{
  constexpr int NWG = 784;
  __shared__ __align__(16) u16 As[3][4096];   // 128 rows x 32 k
  __shared__ __align__(16) u16 Bs[3][6144];   // 192 rows x 32 k
  int tid = threadIdx.x;
  int wg = blockIdx.x;
  int lin = (wg & 7) * (NWG / 8) + (wg >> 3);
  int tileM = lin * 128;
  int lane = tid & 63, wave = tid >> 6;
  int g = lane >> 4, l15 = lane & 15;
  f32x4 acc[2][12] = {};

  int r0 = tid >> 2, kc = (tid & 3) * 8;
  const u16* Arow0 = A + (size_t)(tileM + r0)      * 192 + kc;
  const u16* Arow1 = A + (size_t)(tileM + r0 + 64) * 192 + kc;
  const u16* Brow[3];
  #pragma unroll
  for (int i = 0; i < 3; ++i) {
    int s = (wave * 3 + i) * 64 + lane;
    Brow[i] = BT + (size_t)(s >> 2) * 192 + (s & 3) * 8;
  }
  const int wo = wave * 512;

#define PSTAGE(buf, k0) do {                                   \
    gload_lds16(Arow0 + (k0), &As[buf][wo]);                   \
    gload_lds16(Arow1 + (k0), &As[buf][2048 + wo]);            \
    _Pragma("unroll")                                          \
    for (int i = 0; i < 3; ++i)                                \
      gload_lds16(Brow[i] + (k0), &Bs[buf][(wave * 3 + i) * 512]); \
  } while (0)

  PSTAGE(0, 0);
  PSTAGE(1, 32);

  #pragma unroll
  for (int t = 0; t < 6; ++t) {
    if (t + 1 < 6) asm volatile("s_waitcnt vmcnt(5)" ::: "memory");
    else           asm volatile("s_waitcnt vmcnt(0)" ::: "memory");
    __builtin_amdgcn_s_barrier();
    __builtin_amdgcn_sched_barrier(0);
    if (t + 2 < 6) PSTAGE((t + 2) % 3, (t + 2) * 32);
    const int cur = t % 3;
    bf16x8 af[2], bfr[12];
    #pragma unroll
    for (int mi = 0; mi < 2; ++mi)
      af[mi] = *(const bf16x8*)&As[cur][(wave * 32 + mi * 16 + l15) * 32 + g * 8];
    #pragma unroll
    for (int ni = 0; ni < 12; ++ni)
      bfr[ni] = *(const bf16x8*)&Bs[cur][(ni * 16 + l15) * 32 + g * 8];
    #pragma unroll
    for (int mi = 0; mi < 2; ++mi)
      #pragma unroll
      for (int ni = 0; ni < 12; ++ni)
        acc[mi][ni] = __builtin_amdgcn_mfma_f32_16x16x32_bf16(bfr[ni], af[mi], acc[mi][ni], 0, 0, 0);
    __builtin_amdgcn_sched_barrier(0);
  }
#undef PSTAGE

  float s1[2] = {0.f, 0.f}, s2[2] = {0.f, 0.f};
  #pragma unroll
  for (int mi = 0; mi < 2; ++mi) {
    size_t row = (size_t)(tileM + wave * 32 + mi * 16 + l15);
    #pragma unroll
    for (int ni = 0; ni < 12; ++ni) {
      int cb = ni * 16 + g * 4;
      f32x4 bv = *(const f32x4*)&bias[cb];
      f32x4 xv = *(const f32x4*)&x[row * 192 + cb];
      f32x4 o;
      #pragma unroll
      for (int r = 0; r < 4; ++r) {
        o[r] = acc[mi][ni][r] + bv[r] + xv[r];
        s1[mi] += o[r];
        s2[mi] += o[r] * o[r];
      }
      acc[mi][ni] = o;
      uint2 w;
      w.x = pk2bf(o[0], o[1]);
      w.y = pk2bf(o[2], o[3]);
      *(uint2*)&resid[row * 192 + cb] = w;     // bf16 resid (halves traffic)
    }
  }
  #pragma unroll
  for (int mi = 0; mi < 2; ++mi) {
    s1[mi] += __shfl_xor(s1[mi], 16); s1[mi] += __shfl_xor(s1[mi], 32);
    s2[mi] += __shfl_xor(s2[mi], 16); s2[mi] += __shfl_xor(s2[mi], 32);
  }
  #pragma unroll
  for (int mi = 0; mi < 2; ++mi) {
    float mu = s1[mi] * (1.f / 192.f);
    float var = s2[mi] * (1.f / 192.f) - mu * mu;
    float rs = rsqrtf(var + 1e-5f);
    size_t row = (size_t)(tileM + wave * 32 + mi * 16 + l15);
    #pragma unroll
    for (int ni = 0; ni < 12; ++ni) {
      int cb = ni * 16 + g * 4;
      f32x4 gv = *(const f32x4*)&n2g[cb];
      f32x4 bv = *(const f32x4*)&n2b[cb];
      uint2 w;
      w.x = pk2bf((acc[mi][ni][0] - mu) * rs * gv[0] + bv[0],
                  (acc[mi][ni][1] - mu) * rs * gv[1] + bv[1]);
      w.y = pk2bf((acc[mi][ni][2] - mu) * rs * gv[2] + bv[2],
                  (acc[mi][ni][3] - mu) * rs * gv[3] + bv[3]);
      *(uint2*)&h2[row * 192 + cb] = w;
    }
  }
}

// -------------------- fused MLP (R14 config: measured best, 137 us) --------------
__global__ __launch_bounds__(256, 3) void mlp_fused(
    const u16* __restrict__ h2, const u16* __restrict__ resid,   // resid bf16
    const u16* __restrict__ w1g,   // swz1 layout
    const u16* __restrict__ w2g,   // swz2 layout
    const float* __restrict__ fc1b, const float* __restrict__ fc2b,
    float* __restrict__ out)
{
  __shared__ __align__(16) u16 W1c[2][6144];   // [32 gc][192 k] swz
  __shared__ __align__(16) u16 W2c[2][6144];   // 768 x 16B granules (swz2 layout)
  __shared__ float B1s[768];
  __shared__ float B2s[192];

  int tid = threadIdx.x, lane = tid & 63, wave = tid >> 6;
  int g = lane >> 4, l15 = lane & 15;
  size_t row = (size_t)blockIdx.x * 64 + wave * 16 + l15;

  for (int c = tid; c < 768; c += 256) B1s[c] = fc1b[c];
  if (tid < 192) B2s[tid] = fc2b[tid];

  bf16x8 xf[6];
  #pragma unroll
  for (int ks = 0; ks < 6; ++ks)
    xf[ks] = *(const bf16x8*)&h2[row * 192 + ks * 32 + g * 8];

#define MSTAGE(c) do {                                                    \
    _Pragma("unroll")                                                     \
    for (int it = 0; it < 3; ++it) {                                      \
      int s = it * 256 + tid;                                             \
      gload_lds16(w1g + (size_t)(c) * 6144 + s * 8,                       \
                  &W1c[(c) & 1][(it * 256 + wave * 64) * 8]);             \
      gload_lds16(w2g + (size_t)(c) * 6144 + s * 8,                       \
                  &W2c[(c) & 1][(it * 256 + wave * 64) * 8]);             \
    }                                                                     \
  } while (0)

  MSTAGE(0);
  __syncthreads();     // drains vmcnt+lgkm: chunk0 + biases ready

  f32x4 accO[12] = {};
  const int p2sw = g ^ ((l15 >> 2) & 3);   // fc2 granule swizzle (lane-const)

  #pragma unroll 2
  for (int c = 0; c < 24; ++c) {
    asm volatile("s_waitcnt vmcnt(0)" ::: "memory");   // chunk c's writes landed
    __builtin_amdgcn_s_barrier();                      // ... in ALL waves
    __builtin_amdgcn_sched_barrier(0);
    if (c + 1 < 24) MSTAGE(c + 1);                     // overwrite after barrier
    const int bs = c & 1;

    // ---- fc1 chunk: acc1[f] r = S[gelu col c*32+f*16+g*4+r][row l15] ----
    f32x4 acc1[2] = {};
    #pragma unroll
    for (int ks = 0; ks < 6; ++ks) {
      #pragma unroll
      for (int f = 0; f < 2; ++f) {
        int rl = f * 16 + l15;
        int sg = (ks * 4 + g) ^ (rl & 7);
        bf16x8 wf = *(const bf16x8*)&W1c[bs][rl * 192 + sg * 8];
        acc1[f] = __builtin_amdgcn_mfma_f32_16x16x32_bf16(wf, xf[ks], acc1[f], 0, 0, 0);
      }
    }
    // ---- bias + gelu + in-lane pack to k=16 B-frags (no LDS round-trip) ----
    short4v bp[2];
    #pragma unroll
    for (int f = 0; f < 2; ++f) {
      f32x4 bv = *(const f32x4*)&B1s[c * 32 + f * 16 + g * 4];
      float p0 = gelu_f(acc1[f][0] + bv[0]);
      float p1 = gelu_f(acc1[f][1] + bv[1]);
      float p2 = gelu_f(acc1[f][2] + bv[2]);
      float p3 = gelu_f(acc1[f][3] + bv[3]);
      union { u32 w[2]; short4v v; } uu;
      uu.w[0] = pk2bf(p0, p1);
      uu.w[1] = pk2bf(p2, p3);
      bp[f] = uu.v;
    }
    // ---- fc2 accumulate: one b128/lane per n, halves feed both k=16 MFMAs ----
    #pragma unroll
    for (int n = 0; n < 12; ++n) {
      int oc = n * 16 + l15;
      int P = oc * 4 + p2sw;
      union { bf16x8 v8; short4v h[2]; } wu;
      wu.v8 = *(const bf16x8*)&W2c[bs][P * 8];
      accO[n] = __builtin_amdgcn_mfma_f32_16x16x16bf16_1k(wu.h[0], bp[0], accO[n], 0, 0, 0);
      accO[n] = __builtin_amdgcn_mfma_f32_16x16x16bf16_1k(wu.h[1], bp[1], accO[n], 0, 0, 0);
    }
    __builtin_amdgcn_sched_barrier(0);   // pin this chunk's reads above next iter
  }
#undef MSTAGE

  // ---- epilogue: out = accO + fc2_b + resid(bf16) (packed f32x4 stores) ----
  const u16* rrow = resid + row * 192;
  float*     orow = out + row * 192;
  #pragma unroll
  for (int n = 0; n < 12; ++n) {
    int cb = n * 16 + g * 4;
    f32x4 bv = *(const f32x4*)&B2s[cb];
    uint2 rv = *(const uint2*)&rrow[cb];
    f32x4 o;
    o[0] = accO[n][0] + bv[0] + bf2f((u16)(rv.x & 0xffff));
    o[1] = accO[n][1] + bv[1] + bf2f((u16)(rv.x >> 16));
    o[2] = accO[n][2] + bv[2] + bf2f((u16)(rv.y & 0xffff));
    o[3] = accO[n][3] + bv[3] + bf2f((u16)(rv.y >> 16));
    *(f32x4*)&orow[cb] = o;
  }
}

// -------------------- MFMA windowed attention v3 (31.7 KB LDS, 1 barrier) -------
__global__ __launch_bounds__(384, 4) void attn_kernel(const u16* __restrict__ qkv,
                                                      const float* __restrict__ rpe,
                                                      u16* __restrict__ aout) {
  __shared__ __align__(16) u16 VT[192 * 72];   // V^T [d][token], pad cols zeroed
  __shared__ float RPE[1014];                  // 169 * 6, pre-scaled by log2e

  int tid = threadIdx.x;
  int win = blockIdx.x;
  int b = win >> 6, rem = win & 63, wh = rem >> 3, ww = rem & 7;
  const size_t wbase = (size_t)b * 3136 + (size_t)(wh * 7) * 56 + ww * 7;

  for (int c = tid; c < 1176; c += 384) {       // 24 d-chunks * 49 tokens (V^T)
    int dchunk = c / 49, tkn = c - dchunk * 49;
    int d0 = dchunk * 8;
    int yi = tkn / 7, xi = tkn - yi * 7;
    size_t t = wbase + yi * 56 + xi;
    uint4 v = *(const uint4*)&qkv[t * 576 + 384 + d0];
    const u16* e = (const u16*)&v;
    #pragma unroll
    for (int u = 0; u < 8; ++u) VT[(d0 + u) * 72 + tkn] = e[u];
  }
  for (int c = tid; c < 2880; c += 384) {       // zero VT pad cols 49..63
    int d = c / 15, n = 49 + (c - d * 15);
    VT[d * 72 + n] = 0;
  }
  for (int c = tid; c < 1014; c += 384) RPE[c] = rpe[c] * LOG2E;
  __syncthreads();

  int wave = tid >> 6, lane = tid & 63;
  int g = lane >> 4, l15 = lane & 15;
  int h = wave;

  bf16x8 afk[4], bfq[4];
  #pragma unroll
  for (int f = 0; f < 4; ++f) {
    int row = f * 16 + l15; row = min(row, 48);
    int y = row / 7, xx = row - y * 7;
    const u16* base = &qkv[(wbase + (size_t)y * 56 + xx) * 576];
    bfq[f] = *(const bf16x8*)(base + h * 32 + g * 8);          // Q (scaled)
    afk[f] = *(const bf16x8*)(base + 192 + h * 32 + g * 8);    // K
  }

  f32x4 acc[4][4] = {};
  __builtin_amdgcn_s_setprio(1);
  #pragma unroll
  for (int mj = 0; mj < 4; ++mj)
    #pragma unroll
    for (int ni = 0; ni < 4; ++ni)
      acc[mj][ni] = __builtin_amdgcn_mfma_f32_16x16x32_bf16(afk[mj], bfq[ni], acc[mj][ni], 0, 0, 0);
  __builtin_amdgcn_s_setprio(0);

  float sums[4];
  short4v bp[4][4];
  #pragma unroll
  for (int ni = 0; ni < 4; ++ni) {
    int i = ni * 16 + l15;
    int yi = i / 7, xi = i - yi * 7;
    #pragma unroll
    for (int mj = 0; mj < 4; ++mj)
      #pragma unroll
      for (int r = 0; r < 4; ++r) {
        int j = mj * 16 + g * 4 + r;
        int yj = j / 7, xj = j - yj * 7;
        int idx = (yi - yj + 6) * 13 + (xi - xj + 6);
        idx = max(0, min(idx, 168));
        float s = acc[mj][ni][r] + RPE[idx * 6 + h];
        acc[mj][ni][r] = (j < 49) ? s : -1e30f;
      }
    float m = -1e30f;
    #pragma unroll
    for (int mj = 0; mj < 4; ++mj) {
      f32x4 a = acc[mj][ni];
      m = fmaxf(m, fmaxf(fmaxf(a[0], a[1]), fmaxf(a[2], a[3])));
    }
    m = fmaxf(m, __shfl_xor(m, 16));
    m = fmaxf(m, __shfl_xor(m, 32));
    float sum = 0.f;
    #pragma unroll
    for (int mj = 0; mj < 4; ++mj) {
      float p0 = exp2f(acc[mj][ni][0] - m);
      float p1 = exp2f(acc[mj][ni][1] - m);
      float p2 = exp2f(acc[mj][ni][2] - m);
      float p3 = exp2f(acc[mj][ni][3] - m);
      sum += (p0 + p1) + (p2 + p3);
      union { u32 w[2]; short4v v; } uu;
      uu.w[0] = pk2bf(p0, p1);
      uu.w[1] = pk2bf(p2, p3);
      bp[ni][mj] = uu.v;
    }
    sum += __shfl_xor(sum, 16);
    sum += __shfl_xor(sum, 32);
    sums[ni] = sum;
  }

  f32x4 accO[2][4] = {};
  #pragma unroll
  for (int ks = 0; ks < 4; ++ks) {
    short4v av[2];
    #pragma unroll
    for (int md = 0; md < 2; ++md)
      av[md] = *(const short4v*)&VT[(h * 32 + md * 16 + l15) * 72 + ks * 16 + g * 4];
    __builtin_amdgcn_s_setprio(1);
    #pragma unroll
    for (int md = 0; md < 2; ++md)
      #pragma unroll
      for (int ni = 0; ni < 4; ++ni)
        accO[md][ni] = __builtin_amdgcn_mfma_f32_16x16x16bf16_1k(av[md], bp[ni][ks], accO[md][ni], 0, 0, 0);
    __builtin_amdgcn_s_setprio(0);
  }

  #pragma unroll
  for (int ni = 0; ni < 4; ++ni) {
    int i = ni * 16 + l15;
    if (i >= 49) continue;
    float inv = __builtin_amdgcn_rcpf(sums[ni]);
    int y = i / 7, xx = i - y * 7;
    u16* orow = &aout[(wbase + (size_t)y * 56 + xx) * 192 + h * 32];
    #pragma unroll
    for (int md = 0; md < 2; ++md) {
      int d0 = md * 16 + g * 4;
      *(u32*)&orow[d0]     = pk2bf(accO[md][ni][0] * inv, accO[md][ni][1] * inv);
      *(u32*)&orow[d0 + 2] = pk2bf(accO[md][ni][2] * inv, accO[md][ni][3] * inv);
    }
  }
}

// -------------------- host launch --------------------
extern "C" void kernel_launch(void* const* d_in, const int* in_sizes, int n_in,
                              void* d_out, int out_size, void* d_ws, size_t ws_size,
                              hipStream_t stream) {
  const float* x      = (const float*)d_in[0];
  const float* n1g    = (const float*)d_in[1];
  const float* n1b    = (const float*)d_in[2];
  const float* qkv_w  = (const float*)d_in[3];
  const float* qkv_b  = (const float*)d_in[4];
  const float* rpe    = (const float*)d_in[5];
  const float* proj_w = (const float*)d_in[6];
  const float* proj_b = (const float*)d_in[7];
  const float* n2g    = (const float*)d_in[8];
  const float* n2b    = (const float*)d_in[9];
  const float* fc1_w  = (const float*)d_in[10];
  const float* fc1_b  = (const float*)d_in[11];
  const float* fc2_w  = (const float*)d_in[12];
  const float* fc2_b  = (const float*)d_in[13];
  float* out = (float*)d_out;
  char* ws = (char*)d_ws;

  // workspace layout (bytes):
  u16* qkvT  = (u16*)(ws + 0);            //  640x192 bf16      [0 .. 245760)
  u16* projT = (u16*)(ws + 245760);       //  256x192           [.. 344064)
  u16* fc1T  = (u16*)(ws + 344064);       //  768x192 swz       [.. 638976)
  u16* fc2T  = (u16*)(ws + 638976);       //  24x768x8 swz      [.. 933888)
  u16* ln1   = (u16*)(ws + 1048576);      //  TOKx192 bf16; reused as attn_out
  u16* qkvB  = (u16*)(ws + 39583744);     //  TOKx576 bf16; head reused as h2
  u16* resid = (u16*)(ws + 78118912);     //  TOKx192 bf16 (38.5MB)
  u16* attnO = ln1;
  u16* h2    = qkvB;
  if (ws_size < 193724416u) return;

  prep_weights<<<1824, 256, 0, stream>>>(qkv_w, proj_w, fc1_w, fc2_w,
                                         qkvT, projT, fc1T, fc2T);

  ln_kernel<<<TOK/4, 256, 0, stream>>>(x, n1g, n1b, ln1);

  // QKV: M=TOK (784 tiles), N=576 (5 tiles), K=192  (R17 config)
  gemm_kernel<MQKV, 784, 5, 576, 192, 576><<<3920, 256, 0, stream>>>(
      ln1, qkvT, qkv_b, qkvB);

  attn_kernel<<<2048, 384, 0, stream>>>(qkvB, rpe, attnO);

  // fused proj + residual + LN2 (resid stored bf16)
  proj_ln<<<784, 256, 0, stream>>>(
      attnO, projT, proj_b, x, n2g, n2b, resid, h2);

  // fused MLP: 4 waves x 16 rows, 64 rows/block, 1568 blocks (R14 config)
  mlp_fused<<<TOK/64, 256, 0, stream>>>(
      h2, resid, fc1T, fc2T, fc1_b, fc2_b, out);
}